// Round 8
// baseline (653.633 us; speedup 1.0000x reference)
//
#include <hip/hip_runtime.h>
#include <hip/hip_bf16.h>

// Problem constants
#define BB   128
#define DV   2048
#define SS   196
#define DQ   2048
#define DA   1200
#define DAP  1280      // DA padded to 5*256 MFMA n-tiles
#define GG   4
#define DH   2048
#define NANS 3000
#define NANSP 3008     // 47*64
#define MROWS (BB*SS)  // 25088 = 196 * 128 exactly
#define NT   5         // n-tiles (256-wide) in big GEMM
#define KSPLIT 8
#define KCHUNK (DV/KSPLIT)  // 256
#define NQ   (DAP + DH)     // 3328 merged q-branch cols

typedef __attribute__((ext_vector_type(8))) short bf16x8;
typedef __attribute__((ext_vector_type(4))) float f32x4;

__device__ __forceinline__ float fast_tanh(float x) {
    float e = __expf(2.0f * x);
    return 1.0f - 2.0f * __builtin_amdgcn_rcpf(e + 1.0f);
}

__device__ __forceinline__ void async_copy16(const void* gsrc, void* ldst) {
    __builtin_amdgcn_global_load_lds(
        (const __attribute__((address_space(1))) void*)gsrc,
        (__attribute__((address_space(3))) void*)ldst, 16, 0, 0);
}

#define VM6 asm volatile("s_waitcnt vmcnt(6)" ::: "memory")
#define VM4 asm volatile("s_waitcnt vmcnt(4)" ::: "memory")
#define VM0 asm volatile("s_waitcnt vmcnt(0)" ::: "memory")
#define BAR __builtin_amdgcn_s_barrier()

// ---------------------------------------------------------------------------
// fp32 split-K partial GEMM body (shared by standalone kernel and front).
// Staging vectorized: A 8x float4 along k, B 4x float4 along n (G13).
// SEL 0: classifier | SEL 1: glimpse fusion | SEL 2: merged q-branch.
// ---------------------------------------------------------------------------
template <int SEL>
__device__ __forceinline__ void gemm_body(
    int bx, int by, int t,
    const float* __restrict__ A, int lda,
    const float* __restrict__ Bm, const float* __restrict__ B2,
    float* __restrict__ Cp, int Npad,
    float* As, float* Bs) {
    const int n0    = bx * 64;
    const int kbase = by * KCHUNK;

    const float* Aeff = A;
    const float* Beff;
    int ldb, ncol0, nlim;
    if (SEL == 0) {            // classifier: B=Wc [2048][3000]
        Beff = Bm; ldb = NANS; ncol0 = n0; nlim = NANS;
    } else if (SEL == 1) {     // fusion: A=vatt per glimpse, B=Wf[g] [2048][512]
        int gg = n0 >> 9;
        Aeff = A + gg * 2048;
        Beff = Bm + (size_t)gg * 2048 * 512;
        ldb = 512; ncol0 = n0 & 511; nlim = 1 << 30;
    } else {                   // merged q-branch
        if (n0 < DAP) { Beff = Bm; ldb = DA; ncol0 = n0;      nlim = DA; }
        else          { Beff = B2; ldb = DH; ncol0 = n0 - DAP; nlim = 1 << 30; }
    }

    const int tm = (t & 31) * 4;
    const int tn = (t >> 5) * 8;
    const int sm = t >> 1, kq = t & 1;          // A staging: 8 float4 along k
    const int bk = t >> 4, bn4 = (t & 15) * 4;  // B staging: 4 float4 along n
    const bool bok = (ncol0 + bn4 + 3) < nlim;  // nlim % 4 == 0 for all SEL
    float acc[4][8] = {};

    for (int k0 = kbase; k0 < kbase + KCHUNK; k0 += 64) {
        {
            const float* Ap = Aeff + (size_t)sm * lda + k0 + kq * 32;
#pragma unroll
            for (int i = 0; i < 8; ++i) {
                float4 a4 = *(const float4*)(Ap + i * 4);
                int kk = kq * 32 + i * 4;
                As[(kk + 0) * 132 + sm] = a4.x;
                As[(kk + 1) * 132 + sm] = a4.y;
                As[(kk + 2) * 132 + sm] = a4.z;
                As[(kk + 3) * 132 + sm] = a4.w;
            }
        }
        {
#pragma unroll
            for (int i = 0; i < 4; ++i) {
                int k = bk + i * 16;
                float4 b4 = bok
                    ? *(const float4*)(Beff + (size_t)(k0 + k) * ldb + ncol0 + bn4)
                    : (float4){0.f, 0.f, 0.f, 0.f};
                *(float4*)(Bs + k * 68 + bn4) = b4;
            }
        }
        __syncthreads();
#pragma unroll
        for (int kk = 0; kk < 64; ++kk) {
            const float4 av = *(const float4*)(As + kk * 132 + tm);
            const float4 b0 = *(const float4*)(Bs + kk * 68 + tn);
            const float4 b1 = *(const float4*)(Bs + kk * 68 + tn + 4);
            const float am[4] = {av.x, av.y, av.z, av.w};
#pragma unroll
            for (int i = 0; i < 4; ++i) {
                acc[i][0] += am[i] * b0.x; acc[i][1] += am[i] * b0.y;
                acc[i][2] += am[i] * b0.z; acc[i][3] += am[i] * b0.w;
                acc[i][4] += am[i] * b1.x; acc[i][5] += am[i] * b1.y;
                acc[i][6] += am[i] * b1.z; acc[i][7] += am[i] * b1.w;
            }
        }
        __syncthreads();
    }
#pragma unroll
    for (int i = 0; i < 4; ++i) {
        size_t base = ((size_t)by * 128 + tm + i) * Npad + n0 + tn;
        float4 v0 = {acc[i][0], acc[i][1], acc[i][2], acc[i][3]};
        float4 v1 = {acc[i][4], acc[i][5], acc[i][6], acc[i][7]};
        *(float4*)(Cp + base) = v0;
        *(float4*)(Cp + base + 4) = v1;
    }
}

template <int SEL>
__global__ __launch_bounds__(256) void gemm_partial(
    const float* __restrict__ A, int lda,
    const float* __restrict__ Bm, const float* __restrict__ B2,
    float* __restrict__ Cp, int Npad) {
    __shared__ __align__(16) float As[64 * 132];
    __shared__ __align__(16) float Bs[64 * 68];
    gemm_body<SEL>(blockIdx.x, blockIdx.y, threadIdx.x, A, lda, Bm, B2, Cp,
                   Npad, As, Bs);
}

// ---------------------------------------------------------------------------
// front: merged independent front-end work in ONE launch, block-partitioned:
//   [0,416)            q-branch GEMM (long pole, starts first)
//   [416,1056)         transpose_w
//   [1056,1076)        pad_misc
//   [1076,1076+26624)  transpose_v (memory-bound; overlaps q-GEMM's VALU)
// All partitions are mutually independent (no shared state, per-block sync
// only). Overlapping them is the only way to co-execute on one stream.
// ---------------------------------------------------------------------------
__global__ __launch_bounds__(256) void front(
    const float* __restrict__ bv, const float* __restrict__ Wa,
    float* __restrict__ bvp, float* __restrict__ wap,
    const float* __restrict__ Wv, __hip_bfloat16* __restrict__ wvt,
    const float* __restrict__ x_q, const float* __restrict__ Wq_att,
    const float* __restrict__ Wqf, float* __restrict__ Cp,
    const float* __restrict__ v, __hip_bfloat16* __restrict__ vt) {
    __shared__ __align__(16) float shmem[64 * 132 + 64 * 68];  // 51.2 KB
    const int t = threadIdx.x;
    int bid = blockIdx.x;
    if (bid < 416) {
        // merged q-branch GEMM: bx = bid % 52 (NQ/64), by = bid / 52 (KSPLIT)
        gemm_body<2>(bid % 52, bid / 52, t, x_q, DQ, Wq_att, Wqf, Cp, NQ,
                     shmem, shmem + 64 * 132);
        return;
    }
    bid -= 416;
    if (bid < 640) {
        // transpose_w: Wv [DV][DA] -> wvt [DAP][DV] bf16 (B^T), pad rows 0
        float (*tile)[65] = (float(*)[65])shmem;
        const int d0 = (bid % 20) * 64;
        const int c0 = (bid / 20) * 64;
        const int col  = t & 63;
        const int rowb = t >> 6;
#pragma unroll
        for (int i = 0; i < 16; ++i) {
            int c = rowb + i * 4;
            int d = d0 + col;
            tile[c][col] = (d < DA) ? Wv[(size_t)(c0 + c) * DA + d] : 0.f;
        }
        __syncthreads();
#pragma unroll
        for (int i = 0; i < 16; ++i) {
            int dl = rowb + i * 4;
            wvt[(size_t)(d0 + dl) * DV + c0 + col] = __float2bfloat16(tile[col][dl]);
        }
        return;
    }
    bid -= 640;
    if (bid < 20) {
        // pad bv (DA->DAP) and Wa ([DA][4] -> [DAP][4], pad rows 0)
        int i = bid * 256 + t;
        if (i < DAP) bvp[i] = (i < DA) ? bv[i] : 0.f;
        if (i < DAP * GG) {
            int d = i >> 2;
            wap[i] = (d < DA) ? Wa[i] : 0.f;
        }
        return;
    }
    bid -= 20;
    // transpose_v: v [B][DV][S] fp32 -> vt [(b*S+s)][DV] bf16. No LDS.
    // lane = s_local*4 + cq (16 s x 4 chunks of 8 ch per wave).
    {
        const int cx = bid & 15;            // DV/128 = 16
        const int sy = (bid >> 4) % 13;     // 13 * 16 >= 196
        const int b  = bid / 208;
        const int lane = t & 63;
        const int w    = t >> 6;
        const int sl   = lane >> 2;
        const int cq   = lane & 3;
        const int s    = sy * 16 + sl;
        const int c0   = cx * 128 + w * 32 + cq * 8;
        if (s >= SS) return;
        const float* src = v + (size_t)b * DV * SS + (size_t)c0 * SS + s;
        float f[8];
#pragma unroll
        for (int i = 0; i < 8; ++i) f[i] = src[(size_t)i * SS];
        union { bf16x8 v8; __hip_bfloat16 h[8]; } u;
#pragma unroll
        for (int i = 0; i < 8; ++i) u.h[i] = __float2bfloat16(f[i]);
        *(bf16x8*)(vt + ((size_t)b * SS + s) * DV + c0) = u.v8;
    }
}

// Generic epilogue: MODE 0: +bias (classifier) | MODE 2: MLB glimpse fusion
template <int MODE>
__global__ __launch_bounds__(256) void gemm_epilogue(
    const float* __restrict__ Cp, int Npad, int Nreal,
    const float* __restrict__ bias, const float* __restrict__ aux,
    float* __restrict__ out, int ldo) {
    int n = blockIdx.x * 256 + threadIdx.x;
    int m = blockIdx.y;
    if (n >= Npad) return;
    float s = 0.f;
#pragma unroll
    for (int ks = 0; ks < KSPLIT; ++ks)
        s += Cp[((size_t)ks * 128 + m) * Npad + n];
    if (MODE == 0) {
        if (n >= Nreal) return;
        out[(size_t)m * ldo + n] = s + bias[n];
    } else {
        float xv = fast_tanh(s + bias[n]);
        out[(size_t)m * ldo + n] = fast_tanh(xv * aux[(size_t)m * 2048 + n]);
    }
}

// q-branch epilogue: cols [0,DAP) -> qatt (tanh, pad->0), [DAP,NQ) -> qfus
__global__ __launch_bounds__(256) void epilogue_q(
    const float* __restrict__ Cp,
    const float* __restrict__ bqa, const float* __restrict__ bqf,
    float* __restrict__ qatt, float* __restrict__ qfus) {
    int n = blockIdx.x * 256 + threadIdx.x;
    int m = blockIdx.y;
    if (n >= NQ) return;
    float s = 0.f;
#pragma unroll
    for (int ks = 0; ks < KSPLIT; ++ks)
        s += Cp[((size_t)ks * 128 + m) * NQ + n];
    if (n < DAP) {
        qatt[(size_t)m * DAP + n] = (n < DA) ? fast_tanh(s + bqa[n]) : 0.f;
    } else {
        int j = n - DAP;
        qfus[(size_t)m * DH + j] = fast_tanh(s + bqf[j]);
    }
}

// ---------------------------------------------------------------------------
// K1: big MFMA GEMM, 256x256 tile, BK=64, 8 waves (2M x 4N).
// Loop restructured as 16 iterations x 2 K-tiles (even->buf0, odd->buf1,
// both unrolled) so EVERY LDS offset and stage offset is a compile-time
// constant (folded into instruction offset fields) -- kills the ~28%
// VALUBusy of runtime address math (m201's 2-tiles/iter trick). Global
// stage addresses: two running per-thread pointers aS/bS advanced +256 B
// per iteration; per-item offsets are literals (+128/+256/+384, ks +64).
// Stage schedule / vmcnt(6) ledger / barrier placement are IDENTICAL to
// the r6/r7 kernel (proven 3 rounds): per tile T: p0 stages (T+1,B.ks0),
// p1 stages (T+1,A.ks1) + vmcnt(6) + barrier, p2 stages (T+1,B.ks1),
// p3 stages (T+2,A.ks0) + vmcnt(6) + barrier. Prologue: 5 items, vmcnt(6).
// Tail peeled: kt=30 (no p3 stage, vmcnt(4)), kt=31 (no stages, vmcnt(0)).
// Swizzle: stored chunk = g ^ ((row>>1)&3); gload_lds dest lane-linear,
// source pre-swizzled. Fused epilogue -> scores_p (no atomics).
// ---------------------------------------------------------------------------
__global__ __launch_bounds__(512, 2) void big_gemm(
    const __hip_bfloat16* __restrict__ vt,
    const __hip_bfloat16* __restrict__ wt,
    const float* __restrict__ bvp,
    const float* __restrict__ qatt,
    const float* __restrict__ wap,
    float* __restrict__ scores_p) {
    // lds: buf*65536 + ks*32768 + mat*16384 + row*64 + chunk*16  (bytes)
    __shared__ __align__(16) char lds[131072];
    __shared__ __align__(16) float wa_s[256 * 4];
    __shared__ float qs[3 * 256];

    const int t    = threadIdx.x;
    const int lane = t & 63;
    const int w    = t >> 6;        // wave 0..7
    const int wr   = w >> 2;        // m-half 0..1
    const int wc   = w & 3;         // n-quarter 0..3

    // grid de-swizzle: 12 groups of (8 mt x 5 nt) + tail (2 mt x 5 nt)
    int bid = blockIdx.x;
    int grp = bid / 40, r = bid % 40;
    int mt, nt;
    if (grp < 12) { mt = grp * 8 + (r & 7); nt = r >> 3; }
    else          { mt = 96 + (r & 1);      nt = r >> 1; }
    const int m0 = mt * 256, n0 = nt * 256;
    const int b_lo = m0 / SS;              // 256-row tile spans <= 3 batches
    const int bs1  = (b_lo + 1) * SS;
    const int bs2  = (b_lo + 2) * SS;

    // small prologue loads (wa tile, q rows for up to 3 batches)
    if (t < 256) *(float4*)(wa_s + t * 4) = *(const float4*)(wap + (n0 + t) * 4);
    {
        int j = t >> 8, c = t & 255;       // j=0,1 over 512 threads
        int b = b_lo + j;
        qs[t] = (b < BB) ? qatt[(size_t)b * DAP + n0 + c] : 0.f;
        if (t < 256) {
            int b2 = b_lo + 2;
            qs[512 + t] = (b2 < BB) ? qatt[(size_t)b2 * DAP + n0 + t] : 0.f;
        }
    }
    __syncthreads();   // drain prologue vmem so the counted vmcnt is clean

    // Staging: thread t -> row (t>>2) (+128 for 2nd issue), stored chunk t&3.
    // Stored chunk c_st of row R holds global chunk c_st ^ ((R>>1)&3).
    const int srow   = t >> 2;                       // 0..127
    const int schunk = (t & 3) ^ ((t >> 3) & 3);     // pre-swizzled source
    const __hip_bfloat16* aS = vt + (size_t)(m0 + srow) * DV + schunk * 8;
    const __hip_bfloat16* bS = wt + (size_t)(n0 + srow) * DV + schunk * 8;
    char* dst0 = lds + t * 16;

    // stage: 2 issues (rows r, r+128) of one 8KB half; goff in BYTES
    auto ST = [&](const __hip_bfloat16* gbase, int goff, char* dst) {
        const char* g = (const char*)gbase + goff;
        async_copy16(g, dst);
        async_copy16(g + (size_t)128 * DV * 2, dst + 8192);
    };

    // ds_read fragment addressing (bytes)
    const int rchk = ((lane >> 4) ^ (((lane & 15) >> 1) & 3)) * 16;
    const int aRow = (wr * 128 + (lane & 15)) * 64;
    const int bRow = (wc * 64 + (lane & 15)) * 64;
    const char* A0 = lds;
    const char* A1 = lds + 65536;

    f32x4 acc[8][4];
#pragma unroll
    for (int i = 0; i < 8; ++i)
#pragma unroll
        for (int j = 0; j < 4; ++j) acc[i][j] = (f32x4){0.f, 0.f, 0.f, 0.f};

    auto HALF_A = [&](const char* Ar, int mh, bf16x8* afr) {
#pragma unroll
        for (int q = 0; q < 4; ++q)
            afr[q] = *(const bf16x8*)(Ar + aRow + (mh * 64 + q * 16) * 64 + rchk);
    };
    auto HALF_B = [&](const char* Ar, bf16x8* bfr) {
#pragma unroll
        for (int ni = 0; ni < 4; ++ni)
            bfr[ni] = *(const bf16x8*)(Ar + 16384 + bRow + (ni * 16) * 64 + rchk);
    };
    auto MF = [&](int mh, bf16x8* afr, bf16x8* bfr) {
        __builtin_amdgcn_s_setprio(1);
#pragma unroll
        for (int q = 0; q < 4; ++q)
#pragma unroll
            for (int ni = 0; ni < 4; ++ni)
                acc[mh * 4 + q][ni] = __builtin_amdgcn_mfma_f32_16x16x32_bf16(
                    afr[q], bfr[ni], acc[mh * 4 + q][ni], 0, 0, 0);
        __builtin_amdgcn_s_setprio(0);
    };

// One K-tile: XB = read buffer base, NXT/SAME = dst byte offsets (buf^1/buf),
// G1/G2 = global byte offsets of tile T+1 / T+2 relative to aS/bS.
#define TILE8(XB, NXT, SAME, G1, G2, WA, WB)                                   \
    {                                                                          \
        bf16x8 afr[4], bfr[4];                                                 \
        HALF_A((XB), 0, afr); HALF_B((XB), bfr);                               \
        ST(bS, (G1), dst0 + (NXT) + 16384);                                    \
        MF(0, afr, bfr);                                                       \
        HALF_A((XB), 1, afr);                                                  \
        ST(aS, (G1) + 64, dst0 + (NXT) + 32768);                               \
        WA; BAR;                                                               \
        MF(1, afr, bfr);                                                       \
        HALF_A((XB) + 32768, 0, afr); HALF_B((XB) + 32768, bfr);               \
        ST(bS, (G1) + 64, dst0 + (NXT) + 49152);                               \
        MF(0, afr, bfr);                                                       \
        HALF_A((XB) + 32768, 1, afr);                                          \
        ST(aS, (G2), dst0 + (SAME));                                           \
        WB; BAR;                                                               \
        MF(1, afr, bfr);                                                       \
    }

    // prologue: tile0 items 0..3 + tile1 item 0 (10 issues); vmcnt(6) ->
    // (0,0),(0,1) landed; (0,2),(0,3),(1,0) stay in flight.
    ST(aS, 0,   dst0 + 0);
    ST(bS, 0,   dst0 + 16384);
    ST(aS, 64,  dst0 + 32768);
    ST(bS, 64,  dst0 + 49152);
    ST(aS, 128, dst0 + 65536);
    VM6;
    BAR;

    for (int it = 0; it < 15; ++it) {      // kt = 0..29
        TILE8(A0, 65536, 0, 128, 256, VM6, VM6);
        TILE8(A1, 0, 65536, 256, 384, VM6, VM6);
        aS += 128; bS += 128;              // advance 2 tiles (256 B)
    }
    // kt = 30 (buf0): stages (31,1),(31,2),(31,3); no p3 stage; vmcnt(4)
    {
        bf16x8 afr[4], bfr[4];
        HALF_A(A0, 0, afr); HALF_B(A0, bfr);
        ST(bS, 128, dst0 + 65536 + 16384);
        MF(0, afr, bfr);
        HALF_A(A0, 1, afr);
        ST(aS, 192, dst0 + 65536 + 32768);
        VM6; BAR;
        MF(1, afr, bfr);
        HALF_A(A0 + 32768, 0, afr); HALF_B(A0 + 32768, bfr);
        ST(bS, 192, dst0 + 65536 + 49152);
        MF(0, afr, bfr);
        HALF_A(A0 + 32768, 1, afr);
        VM4; BAR;
        MF(1, afr, bfr);
    }
    // kt = 31 (buf1): no stages; vmcnt(0) at p1/p3 (final drain)
    {
        bf16x8 afr[4], bfr[4];
        HALF_A(A1, 0, afr); HALF_B(A1, bfr);
        MF(0, afr, bfr);
        HALF_A(A1, 1, afr);
        VM0; BAR;
        MF(1, afr, bfr);
        HALF_A(A1 + 32768, 0, afr); HALF_B(A1 + 32768, bfr);
        MF(0, afr, bfr);
        HALF_A(A1 + 32768, 1, afr);
        VM0; BAR;
        MF(1, afr, bfr);
    }
#undef TILE8

    // ---- fused epilogue ----
    __syncthreads();                   // staging LDS is now dead
    float* sc = (float*)lds;           // [4][256][4] per-wc partials

    // C/D layout: col = lane&15 (+16*ni), row = (lane>>4)*4 + rr (+16*mi)
    // acc[mi] rows: (mi>>2)*64 + (mi&3)*16 == mi*16 (identical mapping)
    const int colb_l = wc * 64 + (lane & 15);
    const int colb_g = n0 + colb_l;
    float bvv[4];
    float4 wv[4];
#pragma unroll
    for (int ni = 0; ni < 4; ++ni) {
        bvv[ni] = bvp[colb_g + ni * 16];
        wv[ni]  = *(const float4*)(wa_s + (colb_l + ni * 16) * 4);
    }
#pragma unroll
    for (int mi = 0; mi < 8; ++mi) {
#pragma unroll
        for (int rr = 0; rr < 4; ++rr) {
            int lrow = wr * 128 + mi * 16 + ((lane >> 4) << 2) + rr;  // 0..255
            int row  = m0 + lrow;
            int qoff = (row >= bs1 ? 256 : 0) + (row >= bs2 ? 256 : 0);
            float p0 = 0.f, p1 = 0.f, p2 = 0.f, p3 = 0.f;
#pragma unroll
            for (int ni = 0; ni < 4; ++ni) {
                float xv = fast_tanh(acc[mi][ni][rr] + bvv[ni]);
                float xa = fast_tanh(xv * qs[qoff + colb_l + ni * 16]);
                p0 += xa * wv[ni].x; p1 += xa * wv[ni].y;
                p2 += xa * wv[ni].z; p3 += xa * wv[ni].w;
            }
#pragma unroll
            for (int mk = 1; mk < 16; mk <<= 1) {
                p0 += __shfl_xor(p0, mk); p1 += __shfl_xor(p1, mk);
                p2 += __shfl_xor(p2, mk); p3 += __shfl_xor(p3, mk);
            }
            // each (wc, lrow) written exactly once (wr splits lrow ranges)
            if ((lane & 15) == 0)
                *(float4*)(sc + ((size_t)wc * 256 + lrow) * 4) =
                    (float4){p0, p1, p2, p3};
        }
    }
    __syncthreads();
    if (t < 256) {
        float4 s0 = *(float4*)(sc + (0 * 256 + t) * 4);
        float4 s1 = *(float4*)(sc + (1 * 256 + t) * 4);
        float4 s2 = *(float4*)(sc + (2 * 256 + t) * 4);
        float4 s3 = *(float4*)(sc + (3 * 256 + t) * 4);
        float4 s = {s0.x + s1.x + s2.x + s3.x, s0.y + s1.y + s2.y + s3.y,
                    s0.z + s1.z + s2.z + s3.z, s0.w + s1.w + s2.w + s3.w};
        *(float4*)(scores_p + ((size_t)nt * MROWS + m0 + t) * 4) = s;
    }
}

// ---------------------------------------------------------------------------
// K2: sum score partials -> softmax over s -> glimpse pooling (1024-ch chunk,
// 8 B/lane vt loads per G13).
// ---------------------------------------------------------------------------
__global__ __launch_bounds__(256) void softmax_pool(
    const float* __restrict__ scores_p,
    const __hip_bfloat16* __restrict__ vt,
    float* __restrict__ vatt) {
    __shared__ __align__(16) float att[SS * GG];
    const int b = blockIdx.y;
    const int t = threadIdx.x;
    if (t < SS) {
        float4 s = {0.f, 0.f, 0.f, 0.f};
#pragma unroll
        for (int ntile = 0; ntile < NT; ++ntile) {
            float4 p = *(const float4*)(scores_p + ((size_t)ntile * MROWS + b * SS + t) * 4);
            s.x += p.x; s.y += p.y; s.z += p.z; s.w += p.w;
        }
        *(float4*)(att + t * 4) = s;
    }
    __syncthreads();
    {
        const int g = t >> 6;
        const int lane = t & 63;
        float mx = -3.0e38f;
        for (int s = lane; s < SS; s += 64) mx = fmaxf(mx, att[s * 4 + g]);
#pragma unroll
        for (int m = 32; m > 0; m >>= 1) mx = fmaxf(mx, __shfl_xor(mx, m));
        float sum = 0.f;
        for (int s = lane; s < SS; s += 64) sum += __expf(att[s * 4 + g] - mx);
#pragma unroll
        for (int m = 32; m > 0; m >>= 1) sum += __shfl_xor(sum, m);
        float inv = __builtin_amdgcn_rcpf(sum);
        for (int s = lane; s < SS; s += 64) att[s * 4 + g] = __expf(att[s * 4 + g] - mx) * inv;
    }
    __syncthreads();
    const int c = blockIdx.x * 1024 + t * 4;
    const __hip_bfloat16* vp = vt + (size_t)b * SS * DV + c;
    float a0[4] = {}, a1[4] = {}, a2[4] = {}, a3[4] = {};
#pragma unroll 4
    for (int s = 0; s < SS; ++s) {
        uint2 u = *(const uint2*)(vp + (size_t)s * DV);
        float v0 = __uint_as_float(u.x << 16);
        float v1 = __uint_as_float(u.x & 0xffff0000u);
        float v2 = __uint_as_float(u.y << 16);
        float v3 = __uint_as_float(u.y & 0xffff0000u);
        float4 aw = *(const float4*)(att + s * 4);
        a0[0] += v0 * aw.x; a0[1] += v0 * aw.y; a0[2] += v0 * aw.z; a0[3] += v0 * aw.w;
        a1[0] += v1 * aw.x; a1[1] += v1 * aw.y; a1[2] += v1 * aw.z; a1[3] += v1 * aw.w;
        a2[0] += v2 * aw.x; a2[1] += v2 * aw.y; a2[2] += v2 * aw.z; a2[3] += v2 * aw.w;
        a3[0] += v3 * aw.x; a3[1] += v3 * aw.y; a3[2] += v3 * aw.z; a3[3] += v3 * aw.w;
    }
    float* vb = vatt + (size_t)b * GG * DV;
#pragma unroll
    for (int g = 0; g < GG; ++g) {
        float4 o = {a0[g], a1[g], a2[g], a3[g]};
        *(float4*)(vb + (size_t)g * DV + c) = o;
    }
}

// ---------------------------------------------------------------------------
extern "C" void kernel_launch(void* const* d_in, const int* in_sizes, int n_in,
                              void* d_out, int out_size, void* d_ws, size_t ws_size,
                              hipStream_t stream) {
    const float* input_v = (const float*)d_in[0];
    const float* x_q     = (const float*)d_in[1];
    const float* Wv      = (const float*)d_in[2];
    const float* bv      = (const float*)d_in[3];
    const float* Wq_att  = (const float*)d_in[4];
    const float* bq_att  = (const float*)d_in[5];
    const float* Wa      = (const float*)d_in[6];
    // d_in[7] = ba: constant over softmax axis -> cancels, unused.
    const float* Wf      = (const float*)d_in[8];
    const float* bf_     = (const float*)d_in[9];
    const float* Wqf     = (const float*)d_in[10];
    const float* bqf     = (const float*)d_in[11];
    const float* Wc      = (const float*)d_in[12];
    const float* bc      = (const float*)d_in[13];
    float* out = (float*)d_out;

    char* wsb = (char*)d_ws;
    size_t off = 0;
    auto carve = [&](size_t bytes) -> void* {
        void* p = wsb + off;
        off += (bytes + 255) & ~(size_t)255;
        return p;
    };
    __hip_bfloat16* vt  = (__hip_bfloat16*)carve((size_t)MROWS * DV * 2);   // 102.8 MB
    __hip_bfloat16* wvt = (__hip_bfloat16*)carve((size_t)DAP * DV * 2);     //   5.2 MB
    float* Cp       = (float*)carve((size_t)KSPLIT * 128 * NQ * 4);         //  13.6 MB
    float* scores_p = (float*)carve((size_t)NT * MROWS * GG * 4);           //   2.0 MB
    float* qatt = (float*)carve((size_t)BB * DAP * 4);
    float* qfus = (float*)carve((size_t)BB * DH * 4);
    float* bvp  = (float*)carve((size_t)DAP * 4);
    float* wap  = (float*)carve((size_t)DAP * GG * 4);
    float* vatt = (float*)carve((size_t)BB * GG * DV * 4);
    float* xbuf = (float*)carve((size_t)BB * DH * 4);
    (void)ws_size; (void)n_in; (void)in_sizes; (void)out_size;

    // merged front-end: q-GEMM (416) | transpose_w (640) | pad (20) |
    // transpose_v (26624) -- co-scheduled, mutually independent.
    front<<<dim3(416 + 640 + 20 + 26624), 256, 0, stream>>>(
        bv, Wa, bvp, wap, Wv, wvt, x_q, Wq_att, Wqf, Cp, input_v, vt);
    epilogue_q<<<dim3(NQ / 256, BB), 256, 0, stream>>>(Cp, bq_att, bqf, qatt, qfus);

    // big MFMA GEMM with fused score reduction -> scores_p (per-ntile partials)
    big_gemm<<<dim3(490), 512, 0, stream>>>(vt, wvt, bvp, qatt, wap, scores_p);

    // softmax over spatial + glimpse pooling -> vatt [128][4][2048]
    softmax_pool<<<dim3(2, BB), 256, 0, stream>>>(scores_p, vt, vatt);

    // glimpse fusion: xbuf = tanh(tanh(vatt@Wf + bf) * qfus)
    gemm_partial<1><<<dim3(DH / 64, KSPLIT), 256, 0, stream>>>(
        vatt, GG * DV, Wf, nullptr, Cp, DH);
    gemm_epilogue<2><<<dim3(DH / 256, BB), 256, 0, stream>>>(
        Cp, DH, DH, bf_, qfus, xbuf, DH);

    // classifier: out = xbuf @ Wc + bc
    gemm_partial<0><<<dim3(NANSP / 64, KSPLIT), 256, 0, stream>>>(
        xbuf, DH, Wc, nullptr, Cp, NANSP);
    gemm_epilogue<0><<<dim3(NANSP / 256 + 1, BB), 256, 0, stream>>>(
        Cp, NANSP, NANS, bc, nullptr, out, NANS);
}

// Round 9
// 625.253 us; speedup vs baseline: 1.0454x; 1.0454x over previous
//
#include <hip/hip_runtime.h>
#include <hip/hip_bf16.h>

// Problem constants
#define BB   128
#define DV   2048
#define SS   196
#define DQ   2048
#define DA   1200
#define DAP  1280      // DA padded to 5*256 MFMA n-tiles
#define GG   4
#define DH   2048
#define NANS 3000
#define NANSP 3008     // 47*64
#define MROWS (BB*SS)  // 25088 = 196 * 128 exactly
#define NT   5         // n-tiles (256-wide) in big GEMM
#define KSPLIT 8
#define KCHUNK (DV/KSPLIT)  // 256
#define NQ   (DAP + DH)     // 3328 merged q-branch cols

typedef __attribute__((ext_vector_type(8))) short bf16x8;
typedef __attribute__((ext_vector_type(4))) float f32x4;

__device__ __forceinline__ float fast_tanh(float x) {
    float e = __expf(2.0f * x);
    return 1.0f - 2.0f * __builtin_amdgcn_rcpf(e + 1.0f);
}

__device__ __forceinline__ void async_copy16(const void* gsrc, void* ldst) {
    __builtin_amdgcn_global_load_lds(
        (const __attribute__((address_space(1))) void*)gsrc,
        (__attribute__((address_space(3))) void*)ldst, 16, 0, 0);
}

// ---------------------------------------------------------------------------
// fp32 split-K partial GEMM body (shared by standalone kernel and front).
// Staging vectorized: A 8x float4 along k, B 4x float4 along n (G13).
// SEL 0: classifier | SEL 1: glimpse fusion | SEL 2: merged q-branch.
// ---------------------------------------------------------------------------
template <int SEL>
__device__ __forceinline__ void gemm_body(
    int bx, int by, int t,
    const float* __restrict__ A, int lda,
    const float* __restrict__ Bm, const float* __restrict__ B2,
    float* __restrict__ Cp, int Npad,
    float* As, float* Bs) {
    const int n0    = bx * 64;
    const int kbase = by * KCHUNK;

    const float* Aeff = A;
    const float* Beff;
    int ldb, ncol0, nlim;
    if (SEL == 0) {            // classifier: B=Wc [2048][3000]
        Beff = Bm; ldb = NANS; ncol0 = n0; nlim = NANS;
    } else if (SEL == 1) {     // fusion: A=vatt per glimpse, B=Wf[g] [2048][512]
        int gg = n0 >> 9;
        Aeff = A + gg * 2048;
        Beff = Bm + (size_t)gg * 2048 * 512;
        ldb = 512; ncol0 = n0 & 511; nlim = 1 << 30;
    } else {                   // merged q-branch
        if (n0 < DAP) { Beff = Bm; ldb = DA; ncol0 = n0;      nlim = DA; }
        else          { Beff = B2; ldb = DH; ncol0 = n0 - DAP; nlim = 1 << 30; }
    }

    const int tm = (t & 31) * 4;
    const int tn = (t >> 5) * 8;
    const int sm = t >> 1, kq = t & 1;          // A staging: 8 float4 along k
    const int bk = t >> 4, bn4 = (t & 15) * 4;  // B staging: 4 float4 along n
    const bool bok = (ncol0 + bn4 + 3) < nlim;  // nlim % 4 == 0 for all SEL
    float acc[4][8] = {};

    for (int k0 = kbase; k0 < kbase + KCHUNK; k0 += 64) {
        {
            const float* Ap = Aeff + (size_t)sm * lda + k0 + kq * 32;
#pragma unroll
            for (int i = 0; i < 8; ++i) {
                float4 a4 = *(const float4*)(Ap + i * 4);
                int kk = kq * 32 + i * 4;
                As[(kk + 0) * 132 + sm] = a4.x;
                As[(kk + 1) * 132 + sm] = a4.y;
                As[(kk + 2) * 132 + sm] = a4.z;
                As[(kk + 3) * 132 + sm] = a4.w;
            }
        }
        {
#pragma unroll
            for (int i = 0; i < 4; ++i) {
                int k = bk + i * 16;
                float4 b4 = bok
                    ? *(const float4*)(Beff + (size_t)(k0 + k) * ldb + ncol0 + bn4)
                    : (float4){0.f, 0.f, 0.f, 0.f};
                *(float4*)(Bs + k * 68 + bn4) = b4;
            }
        }
        __syncthreads();
#pragma unroll
        for (int kk = 0; kk < 64; ++kk) {
            const float4 av = *(const float4*)(As + kk * 132 + tm);
            const float4 b0 = *(const float4*)(Bs + kk * 68 + tn);
            const float4 b1 = *(const float4*)(Bs + kk * 68 + tn + 4);
            const float am[4] = {av.x, av.y, av.z, av.w};
#pragma unroll
            for (int i = 0; i < 4; ++i) {
                acc[i][0] += am[i] * b0.x; acc[i][1] += am[i] * b0.y;
                acc[i][2] += am[i] * b0.z; acc[i][3] += am[i] * b0.w;
                acc[i][4] += am[i] * b1.x; acc[i][5] += am[i] * b1.y;
                acc[i][6] += am[i] * b1.z; acc[i][7] += am[i] * b1.w;
            }
        }
        __syncthreads();
    }
#pragma unroll
    for (int i = 0; i < 4; ++i) {
        size_t base = ((size_t)by * 128 + tm + i) * Npad + n0 + tn;
        float4 v0 = {acc[i][0], acc[i][1], acc[i][2], acc[i][3]};
        float4 v1 = {acc[i][4], acc[i][5], acc[i][6], acc[i][7]};
        *(float4*)(Cp + base) = v0;
        *(float4*)(Cp + base + 4) = v1;
    }
}

template <int SEL>
__global__ __launch_bounds__(256) void gemm_partial(
    const float* __restrict__ A, int lda,
    const float* __restrict__ Bm, const float* __restrict__ B2,
    float* __restrict__ Cp, int Npad) {
    __shared__ __align__(16) float As[64 * 132];
    __shared__ __align__(16) float Bs[64 * 68];
    gemm_body<SEL>(blockIdx.x, blockIdx.y, threadIdx.x, A, lda, Bm, B2, Cp,
                   Npad, As, Bs);
}

// ---------------------------------------------------------------------------
// front: merged independent front-end work in ONE launch, block-partitioned:
//   [0,416)            q-branch GEMM (long pole, starts first)
//   [416,1056)         transpose_w
//   [1056,1076)        pad_misc
//   [1076,1076+26624)  transpose_v (memory-bound; overlaps q-GEMM's VALU)
// ---------------------------------------------------------------------------
__global__ __launch_bounds__(256) void front(
    const float* __restrict__ bv, const float* __restrict__ Wa,
    float* __restrict__ bvp, float* __restrict__ wap,
    const float* __restrict__ Wv, __hip_bfloat16* __restrict__ wvt,
    const float* __restrict__ x_q, const float* __restrict__ Wq_att,
    const float* __restrict__ Wqf, float* __restrict__ Cp,
    const float* __restrict__ v, __hip_bfloat16* __restrict__ vt) {
    __shared__ __align__(16) float shmem[64 * 132 + 64 * 68];  // 51.2 KB
    const int t = threadIdx.x;
    int bid = blockIdx.x;
    if (bid < 416) {
        // merged q-branch GEMM: bx = bid % 52 (NQ/64), by = bid / 52 (KSPLIT)
        gemm_body<2>(bid % 52, bid / 52, t, x_q, DQ, Wq_att, Wqf, Cp, NQ,
                     shmem, shmem + 64 * 132);
        return;
    }
    bid -= 416;
    if (bid < 640) {
        // transpose_w: Wv [DV][DA] -> wvt [DAP][DV] bf16 (B^T), pad rows 0
        float (*tile)[65] = (float(*)[65])shmem;
        const int d0 = (bid % 20) * 64;
        const int c0 = (bid / 20) * 64;
        const int col  = t & 63;
        const int rowb = t >> 6;
#pragma unroll
        for (int i = 0; i < 16; ++i) {
            int c = rowb + i * 4;
            int d = d0 + col;
            tile[c][col] = (d < DA) ? Wv[(size_t)(c0 + c) * DA + d] : 0.f;
        }
        __syncthreads();
#pragma unroll
        for (int i = 0; i < 16; ++i) {
            int dl = rowb + i * 4;
            wvt[(size_t)(d0 + dl) * DV + c0 + col] = __float2bfloat16(tile[col][dl]);
        }
        return;
    }
    bid -= 640;
    if (bid < 20) {
        // pad bv (DA->DAP) and Wa ([DA][4] -> [DAP][4], pad rows 0)
        int i = bid * 256 + t;
        if (i < DAP) bvp[i] = (i < DA) ? bv[i] : 0.f;
        if (i < DAP * GG) {
            int d = i >> 2;
            wap[i] = (d < DA) ? Wa[i] : 0.f;
        }
        return;
    }
    bid -= 20;
    // transpose_v: v [B][DV][S] fp32 -> vt [(b*S+s)][DV] bf16. No LDS.
    // lane = s_local*4 + cq (16 s x 4 chunks of 8 ch per wave).
    {
        const int cx = bid & 15;            // DV/128 = 16
        const int sy = (bid >> 4) % 13;     // 13 * 16 >= 196
        const int b  = bid / 208;
        const int lane = t & 63;
        const int w    = t >> 6;
        const int sl   = lane >> 2;
        const int cq   = lane & 3;
        const int s    = sy * 16 + sl;
        const int c0   = cx * 128 + w * 32 + cq * 8;
        if (s >= SS) return;
        const float* src = v + (size_t)b * DV * SS + (size_t)c0 * SS + s;
        float f[8];
#pragma unroll
        for (int i = 0; i < 8; ++i) f[i] = src[(size_t)i * SS];
        union { bf16x8 v8; __hip_bfloat16 h[8]; } u;
#pragma unroll
        for (int i = 0; i < 8; ++i) u.h[i] = __float2bfloat16(f[i]);
        *(bf16x8*)(vt + ((size_t)b * SS + s) * DV + c0) = u.v8;
    }
}

// Generic epilogue: MODE 0: +bias (classifier) | MODE 2: MLB glimpse fusion
template <int MODE>
__global__ __launch_bounds__(256) void gemm_epilogue(
    const float* __restrict__ Cp, int Npad, int Nreal,
    const float* __restrict__ bias, const float* __restrict__ aux,
    float* __restrict__ out, int ldo) {
    int n = blockIdx.x * 256 + threadIdx.x;
    int m = blockIdx.y;
    if (n >= Npad) return;
    float s = 0.f;
#pragma unroll
    for (int ks = 0; ks < KSPLIT; ++ks)
        s += Cp[((size_t)ks * 128 + m) * Npad + n];
    if (MODE == 0) {
        if (n >= Nreal) return;
        out[(size_t)m * ldo + n] = s + bias[n];
    } else {
        float xv = fast_tanh(s + bias[n]);
        out[(size_t)m * ldo + n] = fast_tanh(xv * aux[(size_t)m * 2048 + n]);
    }
}

// q-branch epilogue: cols [0,DAP) -> qatt (tanh, pad->0), [DAP,NQ) -> qfus
__global__ __launch_bounds__(256) void epilogue_q(
    const float* __restrict__ Cp,
    const float* __restrict__ bqa, const float* __restrict__ bqf,
    float* __restrict__ qatt, float* __restrict__ qfus) {
    int n = blockIdx.x * 256 + threadIdx.x;
    int m = blockIdx.y;
    if (n >= NQ) return;
    float s = 0.f;
#pragma unroll
    for (int ks = 0; ks < KSPLIT; ++ks)
        s += Cp[((size_t)ks * 128 + m) * NQ + n];
    if (n < DAP) {
        qatt[(size_t)m * DAP + n] = (n < DA) ? fast_tanh(s + bqa[n]) : 0.f;
    } else {
        int j = n - DAP;
        qfus[(size_t)m * DH + j] = fast_tanh(s + bqf[j]);
    }
}

// ---------------------------------------------------------------------------
// K1: big MFMA GEMM, 256x256 tile, BK=64, 8 waves (2M x 4N), 4-phase
// schedule per K-tile (r7 version VERBATIM — benched 158 µs, 36% MfmaUtil):
// reads at phase top, r6 shifted-stage prefetch (vmcnt(6)), barriers only
// at p1/p3 (load-publish points). See r6/r7 ledgers; proven 3 rounds.
// ---------------------------------------------------------------------------
__global__ __launch_bounds__(512, 2) void big_gemm(
    const __hip_bfloat16* __restrict__ vt,
    const __hip_bfloat16* __restrict__ wt,
    const float* __restrict__ bvp,
    const float* __restrict__ qatt,
    const float* __restrict__ wap,
    float* __restrict__ scores_p) {
    // lds: buf*65536 + ks*32768 + mat*16384 + row*64 + chunk*16  (bytes)
    __shared__ __align__(16) char lds[131072];
    __shared__ __align__(16) float wa_s[256 * 4];
    __shared__ float qs[3 * 256];

    const int t    = threadIdx.x;
    const int lane = t & 63;
    const int w    = t >> 6;        // wave 0..7
    const int wr   = w >> 2;        // m-half 0..1
    const int wc   = w & 3;         // n-quarter 0..3

    // grid de-swizzle: 12 groups of (8 mt x 5 nt) + tail (2 mt x 5 nt)
    int bid = blockIdx.x;
    int grp = bid / 40, r = bid % 40;
    int mt, nt;
    if (grp < 12) { mt = grp * 8 + (r & 7); nt = r >> 3; }
    else          { mt = 96 + (r & 1);      nt = r >> 1; }
    const int m0 = mt * 256, n0 = nt * 256;
    const int b_lo = m0 / SS;              // 256-row tile spans <= 3 batches
    const int bs1  = (b_lo + 1) * SS;
    const int bs2  = (b_lo + 2) * SS;

    // small prologue loads (wa tile, q rows for up to 3 batches)
    if (t < 256) *(float4*)(wa_s + t * 4) = *(const float4*)(wap + (n0 + t) * 4);
    {
        int j = t >> 8, c = t & 255;       // j=0,1 over 512 threads
        int b = b_lo + j;
        qs[t] = (b < BB) ? qatt[(size_t)b * DAP + n0 + c] : 0.f;
        if (t < 256) {
            int b2 = b_lo + 2;
            qs[512 + t] = (b2 < BB) ? qatt[(size_t)b2 * DAP + n0 + t] : 0.f;
        }
    }
    __syncthreads();   // drain prologue vmem so the counted vmcnt is clean

    // Staging: thread t -> row (t>>2) (+128 for 2nd issue), stored chunk t&3.
    // Stored chunk c_st of row R holds global chunk c_st ^ ((R>>1)&3).
    const int srow   = t >> 2;                       // 0..127
    const int schunk = (t & 3) ^ ((t >> 3) & 3);     // pre-swizzled source
    const __hip_bfloat16* aG = vt + (size_t)(m0 + srow) * DV + schunk * 8;
    const __hip_bfloat16* bG = wt + (size_t)(n0 + srow) * DV + schunk * 8;

    // stage item p (0..3) of K-tile k into buf k&1: ks=p>>1, mat=p&1 (0=A,1=B)
    auto STAGE_ITEM = [&](int k, int p) {
        const int ks = p >> 1, mat = p & 1;
        const __hip_bfloat16* g = (mat ? bG : aG) + (size_t)k * 64 + ks * 32;
        char* dst = lds + (k & 1) * 65536 + ks * 32768 + mat * 16384 + t * 16;
        async_copy16(g, dst);
        async_copy16(g + (size_t)128 * DV, dst + 8192);
    };

    // ds_read fragment addressing (bytes)
    const int rchk = ((lane >> 4) ^ (((lane & 15) >> 1) & 3)) * 16;
    const int aRow = (wr * 128 + (lane & 15)) * 64;
    const int bRow = (wc * 64 + (lane & 15)) * 64;

    f32x4 acc[8][4];
#pragma unroll
    for (int i = 0; i < 8; ++i)
#pragma unroll
        for (int j = 0; j < 4; ++j) acc[i][j] = (f32x4){0.f, 0.f, 0.f, 0.f};

    // prologue: tile0 items 0..3 + tile1 item 0 (10 issues); vmcnt(6) ->
    // (0,0),(0,1) landed; (0,2),(0,3),(1,0) stay in flight.
    STAGE_ITEM(0, 0); STAGE_ITEM(0, 1);
    STAGE_ITEM(0, 2); STAGE_ITEM(0, 3);
    STAGE_ITEM(1, 0);
    asm volatile("s_waitcnt vmcnt(6)" ::: "memory");
    __builtin_amdgcn_s_barrier();

    for (int kt = 0; kt < 32; ++kt) {
        const int cur = kt & 1;
        const char* Xb = lds + cur * 65536;
        bf16x8 bfr[4];
#pragma unroll
        for (int p = 0; p < 4; ++p) {
            const int ks = p >> 1, mh = p & 1;
            const char* Ar = Xb + ks * 32768;
            bf16x8 afr[4];
#pragma unroll
            for (int q = 0; q < 4; ++q)
                afr[q] = *(const bf16x8*)(Ar + aRow + (mh * 64 + q * 16) * 64 + rchk);
            if (mh == 0) {
#pragma unroll
                for (int ni = 0; ni < 4; ++ni)
                    bfr[ni] = *(const bf16x8*)(Ar + 16384 + bRow + (ni * 16) * 64 + rchk);
            }
            // shifted stage schedule
            if (p < 3) {
                if (kt < 31) STAGE_ITEM(kt + 1, p + 1);
            } else {
                if (kt < 30) STAGE_ITEM(kt + 2, 0);
            }
            if (p == 1) {
                if (kt < 31) asm volatile("s_waitcnt vmcnt(6)" ::: "memory");
                else         asm volatile("s_waitcnt vmcnt(0)" ::: "memory");
                __builtin_amdgcn_s_barrier();
            } else if (p == 3) {
                if (kt < 30)       asm volatile("s_waitcnt vmcnt(6)" ::: "memory");
                else if (kt == 30) asm volatile("s_waitcnt vmcnt(4)" ::: "memory");
                else               asm volatile("s_waitcnt vmcnt(0)" ::: "memory");
                __builtin_amdgcn_s_barrier();
            }
            // p0/p2: no barrier (waves drift within the half-tile)
            __builtin_amdgcn_s_setprio(1);
#pragma unroll
            for (int q = 0; q < 4; ++q)
#pragma unroll
                for (int ni = 0; ni < 4; ++ni)
                    acc[mh * 4 + q][ni] = __builtin_amdgcn_mfma_f32_16x16x32_bf16(
                        afr[q], bfr[ni], acc[mh * 4 + q][ni], 0, 0, 0);
            __builtin_amdgcn_s_setprio(0);
        }
    }

    // ---- fused epilogue ----
    __syncthreads();                   // staging LDS is now dead
    float* sc = (float*)lds;           // [4][256][4] per-wc partials

    // C/D layout: col = lane&15 (+16*ni), row = (lane>>4)*4 + rr (+16*mi)
    const int colb_l = wc * 64 + (lane & 15);
    const int colb_g = n0 + colb_l;
    float bvv[4];
    float4 wv[4];
#pragma unroll
    for (int ni = 0; ni < 4; ++ni) {
        bvv[ni] = bvp[colb_g + ni * 16];
        wv[ni]  = *(const float4*)(wa_s + (colb_l + ni * 16) * 4);
    }
#pragma unroll
    for (int mi = 0; mi < 8; ++mi) {
#pragma unroll
        for (int rr = 0; rr < 4; ++rr) {
            int lrow = wr * 128 + mi * 16 + ((lane >> 4) << 2) + rr;  // 0..255
            int row  = m0 + lrow;
            int qoff = (row >= bs1 ? 256 : 0) + (row >= bs2 ? 256 : 0);
            float p0 = 0.f, p1 = 0.f, p2 = 0.f, p3 = 0.f;
#pragma unroll
            for (int ni = 0; ni < 4; ++ni) {
                float xv = fast_tanh(acc[mi][ni][rr] + bvv[ni]);
                float xa = fast_tanh(xv * qs[qoff + colb_l + ni * 16]);
                p0 += xa * wv[ni].x; p1 += xa * wv[ni].y;
                p2 += xa * wv[ni].z; p3 += xa * wv[ni].w;
            }
#pragma unroll
            for (int mk = 1; mk < 16; mk <<= 1) {
                p0 += __shfl_xor(p0, mk); p1 += __shfl_xor(p1, mk);
                p2 += __shfl_xor(p2, mk); p3 += __shfl_xor(p3, mk);
            }
            // each (wc, lrow) written exactly once (wr splits lrow ranges)
            if ((lane & 15) == 0)
                *(float4*)(sc + ((size_t)wc * 256 + lrow) * 4) =
                    (float4){p0, p1, p2, p3};
        }
    }
    __syncthreads();
    if (t < 256) {
        float4 s0 = *(float4*)(sc + (0 * 256 + t) * 4);
        float4 s1 = *(float4*)(sc + (1 * 256 + t) * 4);
        float4 s2 = *(float4*)(sc + (2 * 256 + t) * 4);
        float4 s3 = *(float4*)(sc + (3 * 256 + t) * 4);
        float4 s = {s0.x + s1.x + s2.x + s3.x, s0.y + s1.y + s2.y + s3.y,
                    s0.z + s1.z + s2.z + s3.z, s0.w + s1.w + s2.w + s3.w};
        *(float4*)(scores_p + ((size_t)nt * MROWS + m0 + t) * 4) = s;
    }
}

// ---------------------------------------------------------------------------
// K2: sum score partials -> softmax over s -> glimpse pooling (1024-ch chunk,
// 8 B/lane vt loads per G13).
// ---------------------------------------------------------------------------
__global__ __launch_bounds__(256) void softmax_pool(
    const float* __restrict__ scores_p,
    const __hip_bfloat16* __restrict__ vt,
    float* __restrict__ vatt) {
    __shared__ __align__(16) float att[SS * GG];
    const int b = blockIdx.y;
    const int t = threadIdx.x;
    if (t < SS) {
        float4 s = {0.f, 0.f, 0.f, 0.f};
#pragma unroll
        for (int ntile = 0; ntile < NT; ++ntile) {
            float4 p = *(const float4*)(scores_p + ((size_t)ntile * MROWS + b * SS + t) * 4);
            s.x += p.x; s.y += p.y; s.z += p.z; s.w += p.w;
        }
        *(float4*)(att + t * 4) = s;
    }
    __syncthreads();
    {
        const int g = t >> 6;
        const int lane = t & 63;
        float mx = -3.0e38f;
        for (int s = lane; s < SS; s += 64) mx = fmaxf(mx, att[s * 4 + g]);
#pragma unroll
        for (int m = 32; m > 0; m >>= 1) mx = fmaxf(mx, __shfl_xor(mx, m));
        float sum = 0.f;
        for (int s = lane; s < SS; s += 64) sum += __expf(att[s * 4 + g] - mx);
#pragma unroll
        for (int m = 32; m > 0; m >>= 1) sum += __shfl_xor(sum, m);
        float inv = __builtin_amdgcn_rcpf(sum);
        for (int s = lane; s < SS; s += 64) att[s * 4 + g] = __expf(att[s * 4 + g] - mx) * inv;
    }
    __syncthreads();
    const int c = blockIdx.x * 1024 + t * 4;
    const __hip_bfloat16* vp = vt + (size_t)b * SS * DV + c;
    float a0[4] = {}, a1[4] = {}, a2[4] = {}, a3[4] = {};
#pragma unroll 4
    for (int s = 0; s < SS; ++s) {
        uint2 u = *(const uint2*)(vp + (size_t)s * DV);
        float v0 = __uint_as_float(u.x << 16);
        float v1 = __uint_as_float(u.x & 0xffff0000u);
        float v2 = __uint_as_float(u.y << 16);
        float v3 = __uint_as_float(u.y & 0xffff0000u);
        float4 aw = *(const float4*)(att + s * 4);
        a0[0] += v0 * aw.x; a0[1] += v0 * aw.y; a0[2] += v0 * aw.z; a0[3] += v0 * aw.w;
        a1[0] += v1 * aw.x; a1[1] += v1 * aw.y; a1[2] += v1 * aw.z; a1[3] += v1 * aw.w;
        a2[0] += v2 * aw.x; a2[1] += v2 * aw.y; a2[2] += v2 * aw.z; a2[3] += v2 * aw.w;
        a3[0] += v3 * aw.x; a3[1] += v3 * aw.y; a3[2] += v3 * aw.z; a3[3] += v3 * aw.w;
    }
    float* vb = vatt + (size_t)b * GG * DV;
#pragma unroll
    for (int g = 0; g < GG; ++g) {
        float4 o = {a0[g], a1[g], a2[g], a3[g]};
        *(float4*)(vb + (size_t)g * DV + c) = o;
    }
}

// ---------------------------------------------------------------------------
extern "C" void kernel_launch(void* const* d_in, const int* in_sizes, int n_in,
                              void* d_out, int out_size, void* d_ws, size_t ws_size,
                              hipStream_t stream) {
    const float* input_v = (const float*)d_in[0];
    const float* x_q     = (const float*)d_in[1];
    const float* Wv      = (const float*)d_in[2];
    const float* bv      = (const float*)d_in[3];
    const float* Wq_att  = (const float*)d_in[4];
    const float* bq_att  = (const float*)d_in[5];
    const float* Wa      = (const float*)d_in[6];
    // d_in[7] = ba: constant over softmax axis -> cancels, unused.
    const float* Wf      = (const float*)d_in[8];
    const float* bf_     = (const float*)d_in[9];
    const float* Wqf     = (const float*)d_in[10];
    const float* bqf     = (const float*)d_in[11];
    const float* Wc      = (const float*)d_in[12];
    const float* bc      = (const float*)d_in[13];
    float* out = (float*)d_out;

    char* wsb = (char*)d_ws;
    size_t off = 0;
    auto carve = [&](size_t bytes) -> void* {
        void* p = wsb + off;
        off += (bytes + 255) & ~(size_t)255;
        return p;
    };
    __hip_bfloat16* vt  = (__hip_bfloat16*)carve((size_t)MROWS * DV * 2);   // 102.8 MB
    __hip_bfloat16* wvt = (__hip_bfloat16*)carve((size_t)DAP * DV * 2);     //   5.2 MB
    float* Cp       = (float*)carve((size_t)KSPLIT * 128 * NQ * 4);         //  13.6 MB
    float* scores_p = (float*)carve((size_t)NT * MROWS * GG * 4);           //   2.0 MB
    float* qatt = (float*)carve((size_t)BB * DAP * 4);
    float* qfus = (float*)carve((size_t)BB * DH * 4);
    float* bvp  = (float*)carve((size_t)DAP * 4);
    float* wap  = (float*)carve((size_t)DAP * GG * 4);
    float* vatt = (float*)carve((size_t)BB * GG * DV * 4);
    float* xbuf = (float*)carve((size_t)BB * DH * 4);
    (void)ws_size; (void)n_in; (void)in_sizes; (void)out_size;

    // merged front-end: q-GEMM (416) | transpose_w (640) | pad (20) |
    // transpose_v (26624) -- co-scheduled, mutually independent.
    front<<<dim3(416 + 640 + 20 + 26624), 256, 0, stream>>>(
        bv, Wa, bvp, wap, Wv, wvt, x_q, Wq_att, Wqf, Cp, input_v, vt);
    epilogue_q<<<dim3(NQ / 256, BB), 256, 0, stream>>>(Cp, bq_att, bqf, qatt, qfus);

    // big MFMA GEMM with fused score reduction -> scores_p (per-ntile partials)
    big_gemm<<<dim3(490), 512, 0, stream>>>(vt, wvt, bvp, qatt, wap, scores_p);

    // softmax over spatial + glimpse pooling -> vatt [128][4][2048]
    softmax_pool<<<dim3(2, BB), 256, 0, stream>>>(scores_p, vt, vatt);

    // glimpse fusion: xbuf = tanh(tanh(vatt@Wf + bf) * qfus)
    gemm_partial<1><<<dim3(DH / 64, KSPLIT), 256, 0, stream>>>(
        vatt, GG * DV, Wf, nullptr, Cp, DH);
    gemm_epilogue<2><<<dim3(DH / 256, BB), 256, 0, stream>>>(
        Cp, DH, DH, bf_, qfus, xbuf, DH);

    // classifier: out = xbuf @ Wc + bc
    gemm_partial<0><<<dim3(NANSP / 64, KSPLIT), 256, 0, stream>>>(
        xbuf, DH, Wc, nullptr, Cp, NANSP);
    gemm_epilogue<0><<<dim3(NANSP / 256 + 1, BB), 256, 0, stream>>>(
        Cp, NANSP, NANS, bc, nullptr, out, NANS);
}